// Round 6
// baseline (104.013 us; speedup 1.0000x reference)
//
#include <hip/hip_runtime.h>
#include <hip/hip_bf16.h>

// FeatureEmbedding: out[b, f+1, e] = sum_d relu(x[b,f]*W1[f,d]+b1[f,d]) * W2[f,d,e] + b2[f,e]
//                   out[b, 0,   e] = cls_token[e]
// B=4096, F=64, D=256. Output f32 [4096][65][256].

#define B_  4096
#define F_  64
#define D_  256
#define ORS (65 * 256)   // out row stride (floats)

using f32x4  = __attribute__((ext_vector_type(4))) float;
using s16x8  = __attribute__((ext_vector_type(8))) short;
typedef unsigned int u32;

__device__ __forceinline__ unsigned short to_bf16_bits(float v) {
    __hip_bfloat16 h = __float2bfloat16(v);
    return *reinterpret_cast<unsigned short*>(&h);
}

__device__ __forceinline__ void gload_lds16(const void* g, void* l) {
    __builtin_amdgcn_global_load_lds(
        (const __attribute__((address_space(1))) u32*)g,
        (__attribute__((address_space(3))) u32*)l, 16, 0, 0);
}

// ---------------------------------------------------------------------------
// Prep: W2 f32 [f][k][e] -> W2s bf16 [f][kb][h][n=e][p'] where each sub-tile
// (kb,h) is 16KB = 256 n-rows of 32 k (64B rows, 4 slots of 8 k).
// Slot swizzle p' = (j&3) ^ ((n>>1)&3): 2-way/free on bfrag ds_read_b128
// (bank = 16*(n&1) + 4*p' mod 32 -> 8 groups x 2 lanes), and a LINEAR 16KB
// copy of the sub-tile into LDS IS the swizzled tile (rule 21).
// ---------------------------------------------------------------------------
__global__ __launch_bounds__(256) void femb_prep(
    const float* __restrict__ W2, unsigned short* __restrict__ W2s)
{
    const int blk = blockIdx.x;        // f*4 + kb
    const int f   = blk >> 2;
    const int kb  = blk & 3;
    const int t   = threadIdx.x;       // owns output column n = t

    const float* col = W2 + (size_t)f * D_ * D_ + (size_t)(kb * 64) * D_ + t;
    float r[64];
    #pragma unroll
    for (int j = 0; j < 64; ++j) r[j] = col[(size_t)j * D_];

    unsigned short* ob = W2s + (size_t)blk * 16384;
    #pragma unroll
    for (int j8 = 0; j8 < 8; ++j8) {
        union { s16x8 s; unsigned short u[8]; } pk;
        #pragma unroll
        for (int e = 0; e < 8; ++e) pk.u[e] = to_bf16_bits(r[j8 * 8 + e]);
        const int h  = j8 >> 2;
        const int pp = (j8 & 3) ^ ((t >> 1) & 3);
        *reinterpret_cast<s16x8*>(ob + h * 8192 + t * 32 + pp * 8) = pk.s;
    }
}

// ---------------------------------------------------------------------------
// Main: one block = (feature, 128-row tile). 256 threads = 4 waves (2x2).
// bid remap: x=bid&7 (XCD), y=(bid>>3)&7, f=x*8+y, row0=(bid>>6)*128.
//  -> all blocks of f on XCD f>>3 (W2s L2 reuse); features 8x..8x+7 on one
//     XCD -> 8KB-contiguous writeback spans per output row.
// K-loop: 8 sub-steps of K=32, double-buffered 16KB global_load_lds staging
// (issue next BEFORE compute). Epilogue: 16 ping-pong 8-row LDS-transpose
// chunks, lgkm-only barriers (stores never drained), 1KB-row stores.
// LDS ~52KB -> 3 blocks/CU.
// ---------------------------------------------------------------------------
__global__ __launch_bounds__(256, 3) void femb_main6(
    const float* __restrict__ x,  const float* __restrict__ W1,
    const float* __restrict__ b1, const unsigned short* __restrict__ W2s,
    const float* __restrict__ b2, const float* __restrict__ cls,
    float* __restrict__ out)
{
    __shared__ float w1s[D_];
    __shared__ float b1s[D_];
    __shared__ float xs[128];
    __shared__ __align__(16) unsigned short bW[2][8192];   // 2 x 16KB staging
    __shared__ __align__(16) float eb[2][8 * 260];         // 2 x 8.3KB epilogue

    const int tid  = threadIdx.x;
    const int bid  = blockIdx.x;
    const int f    = (bid & 7) * 8 + ((bid >> 3) & 7);
    const int row0 = (bid >> 6) << 7;

    w1s[tid] = W1[f * D_ + tid];
    b1s[tid] = b1[f * D_ + tid];
    if (tid < 128) xs[tid] = x[(size_t)(row0 + tid) * F_ + f];

    const int lane = tid & 63;
    const int wid  = tid >> 6;
    const int wm   = wid >> 1;   // row half (64 rows)
    const int wn   = wid & 1;    // col half (128 cols)
    const int llo  = lane & 15;
    const int lhi  = lane >> 4;

    const char* gsrc = (const char*)W2s + (size_t)f * 131072; // 8 sub-tiles * 16KB
    f32x4 clsv = *reinterpret_cast<const f32x4*>(cls + lane * 4);
    f32x4 b2v  = *reinterpret_cast<const f32x4*>(&b2[f * D_ + lane * 4]);

#define STAGE(DST, S)                                                          \
    {                                                                          \
        const char* gt = gsrc + (S) * 16384;                                   \
        _Pragma("unroll")                                                      \
        for (int r = 0; r < 4; ++r)                                            \
            gload_lds16(gt + tid * 16 + r * 4096,                              \
                        (char*)(DST) + tid * 16 + r * 4096);                   \
    }

    STAGE(bW[0], 0);
    __syncthreads();

    float xv[4];
    #pragma unroll
    for (int mt = 0; mt < 4; ++mt) xv[mt] = xs[wm * 64 + mt * 16 + llo];

    f32x4 acc[4][8];
    #pragma unroll
    for (int mt = 0; mt < 4; ++mt)
        #pragma unroll
        for (int nt = 0; nt < 8; ++nt)
            acc[mt][nt] = (f32x4){0.f, 0.f, 0.f, 0.f};

    // bfrag base (shorts) within a 16KB sub-tile:
    // n = wn*128 + nt*16 + llo ; p' = lhi ^ ((llo>>1)&3) ; addr = n*32 + p'*8
    const int bbase = (wn * 128 + llo) * 32 + ((lhi ^ ((llo >> 1) & 3)) * 8);

    #pragma unroll
    for (int s = 0; s < 8; ++s) {
        const unsigned short* cur = bW[s & 1];
        if (s < 7) STAGE(bW[(s & 1) ^ 1], s + 1);   // async; drained at barrier

        const int kg = s * 32 + lhi * 8;
        float w1r[8], b1r[8];
        #pragma unroll
        for (int e = 0; e < 8; ++e) { w1r[e] = w1s[kg + e]; b1r[e] = b1s[kg + e]; }

        s16x8 afrag[4];
        #pragma unroll
        for (int mt = 0; mt < 4; ++mt) {
            union { s16x8 sv; unsigned short u[8]; } pk;
            #pragma unroll
            for (int e = 0; e < 8; ++e) {
                float h = fmaf(xv[mt], w1r[e], b1r[e]);
                pk.u[e] = to_bf16_bits(fmaxf(h, 0.f));
            }
            afrag[mt] = pk.sv;
        }

        #pragma unroll
        for (int nt = 0; nt < 8; ++nt) {
            s16x8 bfrag = *reinterpret_cast<const s16x8*>(&cur[bbase + nt * 512]);
            #pragma unroll
            for (int mt = 0; mt < 4; ++mt)
                acc[mt][nt] = __builtin_amdgcn_mfma_f32_16x16x32_bf16(
                    bfrag, afrag[mt], acc[mt][nt], 0, 0, 0);
        }
        __syncthreads();  // vmcnt drain: next sub-tile ready; fences bW reuse
    }

    // ---- Epilogue: 16 ping-pong chunks of 8 rows; stores never drained ----
    // acc layout: row = wm*64 + mt*16 + llo ; col = wn*128 + nt*16 + lhi*4 + r.
    // Chunk c rows [8c,8c+8): wm==c>>3, mt=(c>>1)&3, llo half = c&1.

#define EPI_WRITE(C, EB)                                                       \
    if (wm == ((C) >> 3) && ((llo >> 3) == ((C) & 1))) {                       \
        const int mt_ = ((C) >> 1) & 3;                                        \
        const int lr_ = llo & 7;                                               \
        _Pragma("unroll")                                                      \
        for (int nt = 0; nt < 8; ++nt)                                         \
            *reinterpret_cast<f32x4*>(                                         \
                &(EB)[lr_ * 260 + wn * 128 + nt * 16 + lhi * 4]) = acc[mt_][nt]; \
    }

#define EPI_BAR()                                                              \
    do {                                                                       \
        asm volatile("s_waitcnt lgkmcnt(0)" ::: "memory");                     \
        __builtin_amdgcn_s_barrier();                                          \
        asm volatile("" ::: "memory");                                         \
    } while (0)

#define EPI_READ(C, EB)                                                        \
    {                                                                          \
        _Pragma("unroll")                                                      \
        for (int i = 0; i < 2; ++i) {                                          \
            const int lr_ = wid * 2 + i;                                       \
            const size_t grow = (size_t)(row0 + (C) * 8 + lr_);                \
            f32x4 v = *reinterpret_cast<const f32x4*>(                         \
                          &(EB)[lr_ * 260 + lane * 4]) + b2v;                  \
            *reinterpret_cast<f32x4*>(out + grow * ORS + (f + 1) * D_ + lane * 4) = v; \
            if (f == 0)                                                        \
                *reinterpret_cast<f32x4*>(out + grow * ORS + lane * 4) = clsv; \
        }                                                                      \
    }

    EPI_WRITE(0, eb[0]);
    EPI_BAR();
    #pragma unroll
    for (int c = 0; c < 16; ++c) {
        float* curb = eb[c & 1];
        float* nxtb = eb[(c & 1) ^ 1];
        if (c < 15) EPI_WRITE(c + 1, nxtb);
        EPI_READ(c, curb);
        if (c < 15) EPI_BAR();
    }
#undef STAGE
#undef EPI_WRITE
#undef EPI_BAR
#undef EPI_READ
}

// ---------------------------------------------------------------------------
// Fallback path (round-1, proven) if ws too small: cls kernel + direct main.
// ---------------------------------------------------------------------------
__global__ void femb_cls(const float* __restrict__ cls, float* __restrict__ out)
{
    int i = blockIdx.x * 256 + threadIdx.x;
    int b = i >> 6;
    int q = i & 63;
    f32x4 v = *reinterpret_cast<const f32x4*>(cls + q * 4);
    *reinterpret_cast<f32x4*>(out + (size_t)b * ORS + q * 4) = v;
}

__global__ __launch_bounds__(256, 2) void femb_main_fb(
    const float* __restrict__ x,  const float* __restrict__ W1,
    const float* __restrict__ b1, const float* __restrict__ W2,
    const float* __restrict__ b2, float* __restrict__ out)
{
    __shared__ float w1s[D_];
    __shared__ float b1s[D_];
    __shared__ float xs[128];
    __shared__ __align__(16) unsigned short bW[256][72];

    const int tid  = threadIdx.x;
    const int bid  = blockIdx.x;
    const int f    = bid & 63;
    const int row0 = (bid >> 6) << 7;

    w1s[tid] = W1[f * D_ + tid];
    b1s[tid] = b1[f * D_ + tid];
    if (tid < 128) xs[tid] = x[(size_t)(row0 + tid) * F_ + f];

    const int lane = tid & 63;
    const int wid  = tid >> 6;
    const int wm   = wid >> 1;
    const int wn   = wid & 1;
    const int llo  = lane & 15;
    const int lhi  = lane >> 4;

    __syncthreads();

    float xv[4];
    #pragma unroll
    for (int mt = 0; mt < 4; ++mt) xv[mt] = xs[wm * 64 + mt * 16 + llo];

    f32x4 acc[4][8];
    #pragma unroll
    for (int mt = 0; mt < 4; ++mt)
        #pragma unroll
        for (int nt = 0; nt < 8; ++nt)
            acc[mt][nt] = (f32x4){0.f, 0.f, 0.f, 0.f};

    const float* w2col = W2 + (size_t)f * D_ * D_ + tid;

    for (int kb = 0; kb < 4; ++kb) {
        float r[64];
        const float* p = w2col + (size_t)(kb * 64) * D_;
        #pragma unroll
        for (int j = 0; j < 64; ++j) r[j] = p[(size_t)j * D_];

        __syncthreads();
        #pragma unroll
        for (int j8 = 0; j8 < 8; ++j8) {
            union { s16x8 s; unsigned short u[8]; } pk;
            #pragma unroll
            for (int e = 0; e < 8; ++e) pk.u[e] = to_bf16_bits(r[j8 * 8 + e]);
            *reinterpret_cast<s16x8*>(&bW[tid][j8 * 8]) = pk.s;
        }
        __syncthreads();

        #pragma unroll
        for (int ks = 0; ks < 2; ++ks) {
            const int kg = kb * 64 + ks * 32 + lhi * 8;
            float w1r[8], b1r[8];
            #pragma unroll
            for (int e = 0; e < 8; ++e) { w1r[e] = w1s[kg + e]; b1r[e] = b1s[kg + e]; }

            s16x8 afrag[4];
            #pragma unroll
            for (int mt = 0; mt < 4; ++mt) {
                union { s16x8 s; unsigned short u[8]; } pk;
                #pragma unroll
                for (int e = 0; e < 8; ++e) {
                    float h = fmaf(xv[mt], w1r[e], b1r[e]);
                    pk.u[e] = to_bf16_bits(fmaxf(h, 0.f));
                }
                afrag[mt] = pk.s;
            }

            const int kl = ks * 32 + lhi * 8;
            #pragma unroll
            for (int nt = 0; nt < 8; ++nt) {
                s16x8 bfrag = *reinterpret_cast<const s16x8*>(
                    &bW[wn * 128 + nt * 16 + llo][kl]);
                #pragma unroll
                for (int mt = 0; mt < 4; ++mt)
                    acc[mt][nt] = __builtin_amdgcn_mfma_f32_16x16x32_bf16(
                        bfrag, afrag[mt], acc[mt][nt], 0, 0, 0);
            }
        }
    }

    const float* b2f = b2 + f * D_;
    float* obase = out + (size_t)(row0 + wm * 64 + llo) * ORS
                       + (f + 1) * D_ + wn * 128 + lhi * 4;
    #pragma unroll
    for (int nt = 0; nt < 8; ++nt) {
        f32x4 bv = *reinterpret_cast<const f32x4*>(&b2f[wn * 128 + nt * 16 + lhi * 4]);
        #pragma unroll
        for (int mt = 0; mt < 4; ++mt) {
            f32x4 v = acc[mt][nt] + bv;
            *reinterpret_cast<f32x4*>(obase + (size_t)mt * 16 * ORS + nt * 16) = v;
        }
    }
}

extern "C" void kernel_launch(void* const* d_in, const int* in_sizes, int n_in,
                              void* d_out, int out_size, void* d_ws, size_t ws_size,
                              hipStream_t stream)
{
    const float* x   = (const float*)d_in[0];
    const float* W1  = (const float*)d_in[1];
    const float* b1  = (const float*)d_in[2];
    const float* W2  = (const float*)d_in[3];
    const float* b2  = (const float*)d_in[4];
    const float* cls = (const float*)d_in[5];
    float* out = (float*)d_out;

    const size_t need = (size_t)F_ * D_ * D_ * sizeof(unsigned short); // 8 MiB
    if (ws_size >= need) {
        unsigned short* W2s = (unsigned short*)d_ws;
        femb_prep<<<F_ * 4, 256, 0, stream>>>(W2, W2s);
        femb_main6<<<F_ * (B_ / 128), 256, 0, stream>>>(x, W1, b1, W2s, b2, cls, out);
    } else {
        femb_cls<<<(B_ * 64) / 256, 256, 0, stream>>>(cls, out);
        femb_main_fb<<<F_ * (B_ / 128), 256, 0, stream>>>(x, W1, b1, W2, b2, out);
    }
}